// Round 3
// baseline (1544.510 us; speedup 1.0000x reference)
//
#include <hip/hip_runtime.h>

#define E_DIM 512
#define N_DIM 512
#define B_DIM 32
#define H_DIM 8
#define D_DIM 8
#define P3    192   // 3 * H * D

// ---------------------------------------------------------------------------
// K0a: Wt[e][p'] = W_which[p][e] * g_which[e]  (fold LN gamma, transpose)
// plus colsum[p'] = sum_e Wt[e][p']  (for the LN-mean correction in ln_qkv).
// One block per p' (192 blocks).
// ---------------------------------------------------------------------------
__device__ inline float block_reduce_256(float v) {
    __shared__ float red[4];
    #pragma unroll
    for (int m = 32; m >= 1; m >>= 1) v += __shfl_xor(v, m);
    int w = threadIdx.x >> 6;
    if ((threadIdx.x & 63) == 0) red[w] = v;
    __syncthreads();
    if (threadIdx.x == 0) v = red[0] + red[1] + red[2] + red[3];
    return v;
}

__global__ __launch_bounds__(256) void prep_wt(const float* __restrict__ Wq,
                        const float* __restrict__ Wk, const float* __restrict__ Wv,
                        const float* __restrict__ gq, const float* __restrict__ gk,
                        const float* __restrict__ gv,
                        float* __restrict__ Wt, float* __restrict__ colsum) {
    int pp = blockIdx.x;     // 192
    int which = pp >> 6, p = pp & 63;
    const float* W = (which == 0) ? Wq : (which == 1) ? Wk : Wv;
    const float* g = (which == 0) ? gq : (which == 1) ? gk : gv;
    int t = threadIdx.x;
    float s = 0.f;
    #pragma unroll
    for (int l = 0; l < 2; ++l) {
        int e = t + l * 256;
        float w = W[p * E_DIM + e] * g[e];
        Wt[e * P3 + pp] = w;
        s += w;
    }
    s = block_reduce_256(s);
    if (t == 0) colsum[pp] = s;
}

// ---------------------------------------------------------------------------
// K0b: b2[p'] = proj_bias[p] + dot(W_which[p,:], ln_beta_which)
// ---------------------------------------------------------------------------
__global__ __launch_bounds__(256) void prep_b2(const float* __restrict__ Wq,
                        const float* __restrict__ Wk, const float* __restrict__ Wv,
                        const float* __restrict__ bnq, const float* __restrict__ bnk,
                        const float* __restrict__ bnv,
                        const float* __restrict__ bq, const float* __restrict__ bk,
                        const float* __restrict__ bv,
                        float* __restrict__ b2) {
    int pp = blockIdx.x;     // 192
    int which = pp >> 6, p = pp & 63;
    const float* W  = (which == 0) ? Wq  : (which == 1) ? Wk  : Wv;
    const float* bn = (which == 0) ? bnq : (which == 1) ? bnk : bnv;
    const float* bb = (which == 0) ? bq  : (which == 1) ? bk  : bv;
    int t = threadIdx.x;
    float s = W[p * E_DIM + t] * bn[t] + W[p * E_DIM + t + 256] * bn[t + 256];
    s = block_reduce_256(s);
    if (t == 0) b2[pp] = s + bb[p];
}

// ---------------------------------------------------------------------------
// K3: Wl2[h*4096 + n*8 + d] = sum_e Wl[n*512+e] * Wo[e*64 + h*8 + d]
// ---------------------------------------------------------------------------
__global__ __launch_bounds__(64) void prep_wl2(const float* __restrict__ Wl,
                                               const float* __restrict__ Wo,
                                               float* __restrict__ Wl2) {
    __shared__ float row[E_DIM];
    int n = blockIdx.x, t = threadIdx.x;
    #pragma unroll
    for (int l = 0; l < 8; ++l) row[t + l * 64] = Wl[n * E_DIM + t + l * 64];
    __syncthreads();
    float s = 0.f;
    #pragma unroll 4
    for (int e = 0; e < E_DIM; ++e) s += row[e] * Wo[e * 64 + t];
    Wl2[(t >> 3) * (N_DIM * D_DIM) + n * D_DIM + (t & 7)] = s;
}

// ---------------------------------------------------------------------------
// K3b: partials[blk] = partial sum of bo[f&511] * Wl[f]  (64 blocks)
// ---------------------------------------------------------------------------
__global__ __launch_bounds__(256) void prep_c0(const float* __restrict__ Wl,
                                               const float* __restrict__ bo,
                                               float* __restrict__ partials) {
    int f0 = blockIdx.x * 4096 + threadIdx.x;
    float s = 0.f;
    #pragma unroll
    for (int l = 0; l < 16; ++l) {
        int f = f0 + l * 256;
        s += Wl[f] * bo[f & 511];
    }
    s = block_reduce_256(s);
    if (threadIdx.x == 0) partials[blockIdx.x] = s;
}

// ---------------------------------------------------------------------------
// K1: fused LN + QKV projection, LDS-tiled GEMM, single pass over x.
// Block = 256 threads, 32 rows. acc_raw = sum x*w; LN applied at epilogue:
//   xhat@W = rs*(acc_raw - mean*colsum) + b2.
// Row stats (sum x, sum x^2) accumulated during A-tile staging.
// Wt tile staged in LDS once per block (not once per wave).
// ---------------------------------------------------------------------------
__global__ __launch_bounds__(256, 4) void ln_qkv(const float* __restrict__ x,
                                                 const float* __restrict__ Wt,
                                                 const float* __restrict__ b2,
                                                 const float* __restrict__ colsum,
                                                 float* __restrict__ qkv) {
    __shared__ float At[32 * 32];    // 4 KB   [row][e]
    __shared__ float Bt[32 * P3];    // 24 KB  [e][p']
    __shared__ float stats[32][2];
    const int t = threadIdx.x;
    const int row0 = blockIdx.x * 32;
    const int tx = t & 63, rg = t >> 6;
    const int sr = t >> 3, sc = t & 7;          // staging: row, float4-chunk
    float acc[8][3];
    #pragma unroll
    for (int kk = 0; kk < 8; ++kk) { acc[kk][0] = 0.f; acc[kk][1] = 0.f; acc[kk][2] = 0.f; }
    float sx = 0.f, sxx = 0.f;
    const float4* xrow = (const float4*)(x + (size_t)(row0 + sr) * E_DIM) + sc;

    for (int tile = 0; tile < 16; ++tile) {
        // stage A: 32 rows x 32 e (one float4 per thread) + row-stat accumulation
        float4 av = xrow[tile * 8];
        sx  += av.x + av.y + av.z + av.w;
        sxx += av.x * av.x + av.y * av.y + av.z * av.z + av.w * av.w;
        ((float4*)At)[t] = av;
        // stage B: 32 e-rows x 192 cols = 1536 float4, contiguous in Wt
        const float4* bsrc = (const float4*)(Wt + (size_t)tile * 32 * P3);
        #pragma unroll
        for (int l = 0; l < 6; ++l) ((float4*)Bt)[t + l * 256] = bsrc[t + l * 256];
        __syncthreads();
        #pragma unroll 2
        for (int ee = 0; ee < 32; ee += 4) {
            float4 a[8];
            #pragma unroll
            for (int kk = 0; kk < 8; ++kk)
                a[kk] = *(const float4*)&At[(rg + 4 * kk) * 32 + ee];
            #pragma unroll
            for (int e2 = 0; e2 < 4; ++e2) {
                float w0 = Bt[(ee + e2) * P3 + tx];
                float w1 = Bt[(ee + e2) * P3 + tx + 64];
                float w2 = Bt[(ee + e2) * P3 + tx + 128];
                #pragma unroll
                for (int kk = 0; kk < 8; ++kk) {
                    float xv = (&a[kk].x)[e2];
                    acc[kk][0] += xv * w0;
                    acc[kk][1] += xv * w1;
                    acc[kk][2] += xv * w2;
                }
            }
        }
        __syncthreads();
    }
    // row stats: reduce over the 8 staging lanes of each row
    #pragma unroll
    for (int m = 4; m >= 1; m >>= 1) { sx += __shfl_xor(sx, m); sxx += __shfl_xor(sxx, m); }
    if (sc == 0) {
        float mean = sx * (1.f / E_DIM);
        float var  = sxx * (1.f / E_DIM) - mean * mean;
        stats[sr][0] = mean;
        stats[sr][1] = rsqrtf(var + 1e-5f);
    }
    __syncthreads();
    // epilogue
    float cs0 = colsum[tx], cs1 = colsum[tx + 64], cs2 = colsum[tx + 128];
    float bb0 = b2[tx],     bb1 = b2[tx + 64],     bb2 = b2[tx + 128];
    const size_t BHN8 = (size_t)B_DIM * H_DIM * N_DIM * D_DIM;
    const int h = tx >> 3, d = tx & 7;
    #pragma unroll
    for (int kk = 0; kk < 8; ++kk) {
        int r = rg + 4 * kk;
        float mean = stats[r][0], rs = stats[r][1];
        int ng = row0 + r;
        int b = ng >> 9, n = ng & 511;
        size_t base = (((size_t)(b * H_DIM + h)) * N_DIM + n) * D_DIM + d;
        qkv[base]            = rs * (acc[kk][0] - mean * cs0) + bb0;
        qkv[BHN8 + base]     = rs * (acc[kk][1] - mean * cs1) + bb1;
        qkv[2 * BHN8 + base] = rs * (acc[kk][2] - mean * cs2) + bb2;
    }
}

// ---------------------------------------------------------------------------
// K2: iterative Hopfield retrieval, j-split x4.
// Block = 512 threads, 128 rows of one (b,h); lane group of 4 shares a row,
// each handles j = jj*4 + jq (interleaved -> 4 distinct LDS lines land on
// 4 distinct bank groups, conflict-free broadcasts). Partial (l, aa, ab)
// merged with 2 shfl_xor stages per iteration.
// ---------------------------------------------------------------------------
__global__ __launch_bounds__(512, 8) void hopfield(float* __restrict__ q,
                                                   const float* __restrict__ k,
                                                   const float* __restrict__ v) {
    __shared__ float Kl[N_DIM * D_DIM];
    __shared__ float Vl[N_DIM * D_DIM];
    const int t = threadIdx.x;
    const int bh = blockIdx.x >> 2, quarter = blockIdx.x & 3;
    {
        const float4* ks = (const float4*)(k + (size_t)bh * N_DIM * D_DIM);
        const float4* vs = (const float4*)(v + (size_t)bh * N_DIM * D_DIM);
        #pragma unroll
        for (int l = 0; l < 2; ++l) {
            ((float4*)Kl)[l * 512 + t] = ks[l * 512 + t];
            ((float4*)Vl)[l * 512 + t] = vs[l * 512 + t];
        }
    }
    __syncthreads();
    const int i  = quarter * 128 + (t >> 2);
    const int jq = t & 3;
    float* qrow = q + ((size_t)bh * N_DIM + i) * D_DIM;
    float4 xa = ((const float4*)qrow)[0];
    float4 xb = ((const float4*)qrow)[1];
    const float C = 0.25f * 1.44269504088896f;   // beta * log2(e)

    #pragma unroll 1
    for (int it = 0; it < 4; ++it) {
        const bool last = (it == 3);
        float4 sxa, sxb;
        sxa.x = C * xa.x; sxa.y = C * xa.y; sxa.z = C * xa.z; sxa.w = C * xa.w;
        sxb.x = C * xb.x; sxb.y = C * xb.y; sxb.z = C * xb.z; sxb.w = C * xb.w;
        float l = 0.f;
        float4 aa = {0, 0, 0, 0}, ab = {0, 0, 0, 0};
        #pragma unroll 4
        for (int jj = 0; jj < 128; ++jj) {
            int j = jj * 4 + jq;
            float4 ka = ((const float4*)Kl)[2 * j];
            float4 kb = ((const float4*)Kl)[2 * j + 1];
            float s = sxa.x * ka.x + sxa.y * ka.y + sxa.z * ka.z + sxa.w * ka.w
                    + sxb.x * kb.x + sxb.y * kb.y + sxb.z * kb.z + sxb.w * kb.w;
            float ee = __builtin_amdgcn_exp2f(s);
            l += ee;
            float4 wa, wb;
            if (last) { wa = ((const float4*)Vl)[2 * j]; wb = ((const float4*)Vl)[2 * j + 1]; }
            else      { wa = ka; wb = kb; }
            aa.x += ee * wa.x; aa.y += ee * wa.y; aa.z += ee * wa.z; aa.w += ee * wa.w;
            ab.x += ee * wb.x; ab.y += ee * wb.y; ab.z += ee * wb.z; ab.w += ee * wb.w;
        }
        // merge the 4 j-partials within the lane group
        #pragma unroll
        for (int m = 1; m <= 2; m <<= 1) {
            l    += __shfl_xor(l, m);
            aa.x += __shfl_xor(aa.x, m); aa.y += __shfl_xor(aa.y, m);
            aa.z += __shfl_xor(aa.z, m); aa.w += __shfl_xor(aa.w, m);
            ab.x += __shfl_xor(ab.x, m); ab.y += __shfl_xor(ab.y, m);
            ab.z += __shfl_xor(ab.z, m); ab.w += __shfl_xor(ab.w, m);
        }
        float inv = 1.f / l;
        xa.x = aa.x * inv; xa.y = aa.y * inv; xa.z = aa.z * inv; xa.w = aa.w * inv;
        xb.x = ab.x * inv; xb.y = ab.y * inv; xb.z = ab.z * inv; xb.w = ab.w * inv;
    }
    if (jq == 0) {
        ((float4*)qrow)[0] = xa;
        ((float4*)qrow)[1] = xb;
    }
}

// ---------------------------------------------------------------------------
// K4: y[b] = bl + sum(partials) + dot(o_flat[b], Wl2)
// ---------------------------------------------------------------------------
__global__ __launch_bounds__(256) void finalize(const float* __restrict__ o,
                                                const float* __restrict__ Wl2,
                                                const float* __restrict__ partials,
                                                const float* __restrict__ bl,
                                                float* __restrict__ y) {
    const int b = blockIdx.x;
    const float* ob = o + (size_t)b * (H_DIM * N_DIM * D_DIM);
    float s = 0.f;
    for (int f = threadIdx.x; f < H_DIM * N_DIM * D_DIM; f += 256) s += ob[f] * Wl2[f];
    if (threadIdx.x < 64) s += partials[threadIdx.x];
    s = block_reduce_256(s);
    if (threadIdx.x == 0) y[b] = s + bl[0];
}

// ---------------------------------------------------------------------------
extern "C" void kernel_launch(void* const* d_in, const int* in_sizes, int n_in,
                              void* d_out, int out_size, void* d_ws, size_t ws_size,
                              hipStream_t stream) {
    const float* x   = (const float*)d_in[0];
    const float* g_q = (const float*)d_in[1];
    const float* b_q = (const float*)d_in[2];
    const float* g_k = (const float*)d_in[3];
    const float* b_k = (const float*)d_in[4];
    const float* g_v = (const float*)d_in[5];
    const float* b_v = (const float*)d_in[6];
    const float* Wq  = (const float*)d_in[7];
    const float* bq  = (const float*)d_in[8];
    const float* Wk  = (const float*)d_in[9];
    const float* bk  = (const float*)d_in[10];
    const float* Wv  = (const float*)d_in[11];
    const float* bv  = (const float*)d_in[12];
    const float* Wo  = (const float*)d_in[13];
    const float* bo  = (const float*)d_in[14];
    const float* Wl  = (const float*)d_in[15];
    const float* bl  = (const float*)d_in[16];
    float* out = (float*)d_out;

    float* ws = (float*)d_ws;
    float* Wt       = ws;                   // 98304
    float* b2       = ws + 98304;           // 192
    float* partials = ws + 98496;           // 64
    float* colsum   = ws + 98560;           // 192 (+pad)
    float* Wl2      = ws + 98816;           // 32768
    float* q_t      = ws + 131584;          // 1048576  [B][H][N][8]
    float* k_t      = q_t + 1048576;
    float* v_t      = k_t + 1048576;

    prep_wt <<<192, 256, 0, stream>>>(Wq, Wk, Wv, g_q, g_k, g_v, Wt, colsum);
    prep_b2 <<<192, 256, 0, stream>>>(Wq, Wk, Wv, b_q, b_k, b_v, bq, bk, bv, b2);
    prep_wl2<<<512, 64, 0, stream>>>(Wl, Wo, Wl2);
    prep_c0 <<<64, 256, 0, stream>>>(Wl, bo, partials);
    ln_qkv  <<<512, 256, 0, stream>>>(x, Wt, b2, colsum, q_t);
    hopfield<<<1024, 512, 0, stream>>>(q_t, k_t, v_t);
    finalize<<<32, 256, 0, stream>>>(q_t, Wl2, partials, bl, out);
}

// Round 4
// 396.639 us; speedup vs baseline: 3.8940x; 3.8940x over previous
//
#include <hip/hip_runtime.h>

#define E_DIM 512
#define N_DIM 512
#define B_DIM 32
#define H_DIM 8
#define D_DIM 8
#define P3    192   // 3 * H * D

// ---------------------------------------------------------------------------
__device__ inline float block_reduce_256(float v) {
    __shared__ float red[4];
    #pragma unroll
    for (int m = 32; m >= 1; m >>= 1) v += __shfl_xor(v, m);
    int w = threadIdx.x >> 6;
    if ((threadIdx.x & 63) == 0) red[w] = v;
    __syncthreads();
    if (threadIdx.x == 0) v = red[0] + red[1] + red[2] + red[3];
    return v;
}

// ---------------------------------------------------------------------------
// K0a: Wt[e][p'] = W_which[p][e] * g_which[e]; colsum[p'] = sum_e Wt[e][p']
// ---------------------------------------------------------------------------
__global__ __launch_bounds__(256) void prep_wt(const float* __restrict__ Wq,
                        const float* __restrict__ Wk, const float* __restrict__ Wv,
                        const float* __restrict__ gq, const float* __restrict__ gk,
                        const float* __restrict__ gv,
                        float* __restrict__ Wt, float* __restrict__ colsum) {
    int pp = blockIdx.x;     // 192
    int which = pp >> 6, p = pp & 63;
    const float* W = (which == 0) ? Wq : (which == 1) ? Wk : Wv;
    const float* g = (which == 0) ? gq : (which == 1) ? gk : gv;
    int t = threadIdx.x;
    float s = 0.f;
    #pragma unroll
    for (int l = 0; l < 2; ++l) {
        int e = t + l * 256;
        float w = W[p * E_DIM + e] * g[e];
        Wt[e * P3 + pp] = w;
        s += w;
    }
    s = block_reduce_256(s);
    if (t == 0) colsum[pp] = s;
}

// ---------------------------------------------------------------------------
// K0b: b2[p'] = proj_bias[p] + dot(W_which[p,:], ln_beta_which)
// ---------------------------------------------------------------------------
__global__ __launch_bounds__(256) void prep_b2(const float* __restrict__ Wq,
                        const float* __restrict__ Wk, const float* __restrict__ Wv,
                        const float* __restrict__ bnq, const float* __restrict__ bnk,
                        const float* __restrict__ bnv,
                        const float* __restrict__ bq, const float* __restrict__ bk,
                        const float* __restrict__ bv,
                        float* __restrict__ b2) {
    int pp = blockIdx.x;     // 192
    int which = pp >> 6, p = pp & 63;
    const float* W  = (which == 0) ? Wq  : (which == 1) ? Wk  : Wv;
    const float* bn = (which == 0) ? bnq : (which == 1) ? bnk : bnv;
    const float* bb = (which == 0) ? bq  : (which == 1) ? bk  : bv;
    int t = threadIdx.x;
    float s = W[p * E_DIM + t] * bn[t] + W[p * E_DIM + t + 256] * bn[t + 256];
    s = block_reduce_256(s);
    if (t == 0) b2[pp] = s + bb[p];
}

// ---------------------------------------------------------------------------
// K3: Wl2[h*4096 + n*8 + d] = sum_e Wl[n*512+e] * Wo[e*64 + h*8 + d]
// ---------------------------------------------------------------------------
__global__ __launch_bounds__(64) void prep_wl2(const float* __restrict__ Wl,
                                               const float* __restrict__ Wo,
                                               float* __restrict__ Wl2) {
    __shared__ float row[E_DIM];
    int n = blockIdx.x, t = threadIdx.x;
    #pragma unroll
    for (int l = 0; l < 8; ++l) row[t + l * 64] = Wl[n * E_DIM + t + l * 64];
    __syncthreads();
    float s = 0.f;
    #pragma unroll 4
    for (int e = 0; e < E_DIM; ++e) s += row[e] * Wo[e * 64 + t];
    Wl2[(t >> 3) * (N_DIM * D_DIM) + n * D_DIM + (t & 7)] = s;
}

// ---------------------------------------------------------------------------
// K3b: partials[blk] = partial sum of bo[f&511] * Wl[f]  (64 blocks)
// ---------------------------------------------------------------------------
__global__ __launch_bounds__(256) void prep_c0(const float* __restrict__ Wl,
                                               const float* __restrict__ bo,
                                               float* __restrict__ partials) {
    int f0 = blockIdx.x * 4096 + threadIdx.x;
    float s = 0.f;
    #pragma unroll
    for (int l = 0; l < 16; ++l) {
        int f = f0 + l * 256;
        s += Wl[f] * bo[f & 511];
    }
    s = block_reduce_256(s);
    if (threadIdx.x == 0) partials[blockIdx.x] = s;
}

// ---------------------------------------------------------------------------
// K1: fused LN + QKV projection, LDS-tiled GEMM, single pass over x.
// ---------------------------------------------------------------------------
__global__ __launch_bounds__(256, 4) void ln_qkv(const float* __restrict__ x,
                                                 const float* __restrict__ Wt,
                                                 const float* __restrict__ b2,
                                                 const float* __restrict__ colsum,
                                                 float* __restrict__ qkv) {
    __shared__ float At[32 * 32];    // 4 KB   [row][e]
    __shared__ float Bt[32 * P3];    // 24 KB  [e][p']
    __shared__ float stats[32][2];
    const int t = threadIdx.x;
    const int row0 = blockIdx.x * 32;
    const int tx = t & 63, rg = t >> 6;
    const int sr = t >> 3, sc = t & 7;
    float acc[8][3];
    #pragma unroll
    for (int kk = 0; kk < 8; ++kk) { acc[kk][0] = 0.f; acc[kk][1] = 0.f; acc[kk][2] = 0.f; }
    float sx = 0.f, sxx = 0.f;
    const float4* xrow = (const float4*)(x + (size_t)(row0 + sr) * E_DIM) + sc;

    for (int tile = 0; tile < 16; ++tile) {
        float4 av = xrow[tile * 8];
        sx  += av.x + av.y + av.z + av.w;
        sxx += av.x * av.x + av.y * av.y + av.z * av.z + av.w * av.w;
        ((float4*)At)[t] = av;
        const float4* bsrc = (const float4*)(Wt + (size_t)tile * 32 * P3);
        #pragma unroll
        for (int l = 0; l < 6; ++l) ((float4*)Bt)[t + l * 256] = bsrc[t + l * 256];
        __syncthreads();
        #pragma unroll 2
        for (int ee = 0; ee < 32; ee += 4) {
            float4 a[8];
            #pragma unroll
            for (int kk = 0; kk < 8; ++kk)
                a[kk] = *(const float4*)&At[(rg + 4 * kk) * 32 + ee];
            #pragma unroll
            for (int e2 = 0; e2 < 4; ++e2) {
                float w0 = Bt[(ee + e2) * P3 + tx];
                float w1 = Bt[(ee + e2) * P3 + tx + 64];
                float w2 = Bt[(ee + e2) * P3 + tx + 128];
                #pragma unroll
                for (int kk = 0; kk < 8; ++kk) {
                    float xv = (&a[kk].x)[e2];
                    acc[kk][0] += xv * w0;
                    acc[kk][1] += xv * w1;
                    acc[kk][2] += xv * w2;
                }
            }
        }
        __syncthreads();
    }
    #pragma unroll
    for (int m = 4; m >= 1; m >>= 1) { sx += __shfl_xor(sx, m); sxx += __shfl_xor(sxx, m); }
    if (sc == 0) {
        float mean = sx * (1.f / E_DIM);
        float var  = sxx * (1.f / E_DIM) - mean * mean;
        stats[sr][0] = mean;
        stats[sr][1] = rsqrtf(var + 1e-5f);
    }
    __syncthreads();
    float cs0 = colsum[tx], cs1 = colsum[tx + 64], cs2 = colsum[tx + 128];
    float bb0 = b2[tx],     bb1 = b2[tx + 64],     bb2 = b2[tx + 128];
    const size_t BHN8 = (size_t)B_DIM * H_DIM * N_DIM * D_DIM;
    const int h = tx >> 3, d = tx & 7;
    #pragma unroll
    for (int kk = 0; kk < 8; ++kk) {
        int r = rg + 4 * kk;
        float mean = stats[r][0], rs = stats[r][1];
        int ng = row0 + r;
        int b = ng >> 9, n = ng & 511;
        size_t base = (((size_t)(b * H_DIM + h)) * N_DIM + n) * D_DIM + d;
        qkv[base]            = rs * (acc[kk][0] - mean * cs0) + bb0;
        qkv[BHN8 + base]     = rs * (acc[kk][1] - mean * cs1) + bb1;
        qkv[2 * BHN8 + base] = rs * (acc[kk][2] - mean * cs2) + bb2;
    }
}

// ---------------------------------------------------------------------------
// K2: iterative Hopfield retrieval, j-split x4, K-only LDS (16 KB).
// Block = 256 threads = 64 rows x 4 j-lanes. Grid = 256 bh x 8 segments
// = 2048 blocks -> 8 blocks/CU (thread-capped), 32 waves/CU.
// 3 iterations vs K (LDS broadcast reads), final association reads V from
// global (128 B contiguous per wave per jj, L1/L2 resident).
// NOTE: no min-wave clamp in launch_bounds — round 3's (512,8) forced
// VGPR=32 and spilled 3 GB to scratch (WRITE_SIZE counter).
// ---------------------------------------------------------------------------
__global__ __launch_bounds__(256) void hopfield(float* __restrict__ q,
                                                const float* __restrict__ k,
                                                const float* __restrict__ v) {
    __shared__ float Kl[N_DIM * D_DIM];   // 16 KB
    const int t = threadIdx.x;
    const int bh = blockIdx.x >> 3, seg = blockIdx.x & 7;
    {
        const float4* ks = (const float4*)(k + (size_t)bh * N_DIM * D_DIM);
        #pragma unroll
        for (int l = 0; l < 4; ++l)
            ((float4*)Kl)[l * 256 + t] = ks[l * 256 + t];
    }
    __syncthreads();
    const int i  = seg * 64 + (t >> 2);
    const int jq = t & 3;
    float* qrow = q + ((size_t)bh * N_DIM + i) * D_DIM;
    float4 xa = ((const float4*)qrow)[0];
    float4 xb = ((const float4*)qrow)[1];
    const float C = 0.25f * 1.44269504088896f;   // beta * log2(e)

    // ---- 3 iterations against K ----
    #pragma unroll 1
    for (int it = 0; it < 3; ++it) {
        float4 sxa, sxb;
        sxa.x = C * xa.x; sxa.y = C * xa.y; sxa.z = C * xa.z; sxa.w = C * xa.w;
        sxb.x = C * xb.x; sxb.y = C * xb.y; sxb.z = C * xb.z; sxb.w = C * xb.w;
        float l = 0.f;
        float4 aa = {0, 0, 0, 0}, ab = {0, 0, 0, 0};
        #pragma unroll 4
        for (int jj = 0; jj < 128; ++jj) {
            int j = jj * 4 + jq;
            float4 ka = ((const float4*)Kl)[2 * j];
            float4 kb = ((const float4*)Kl)[2 * j + 1];
            float s = sxa.x * ka.x + sxa.y * ka.y + sxa.z * ka.z + sxa.w * ka.w
                    + sxb.x * kb.x + sxb.y * kb.y + sxb.z * kb.z + sxb.w * kb.w;
            float ee = __builtin_amdgcn_exp2f(s);
            l += ee;
            aa.x += ee * ka.x; aa.y += ee * ka.y; aa.z += ee * ka.z; aa.w += ee * ka.w;
            ab.x += ee * kb.x; ab.y += ee * kb.y; ab.z += ee * kb.z; ab.w += ee * kb.w;
        }
        #pragma unroll
        for (int m = 1; m <= 2; m <<= 1) {
            l    += __shfl_xor(l, m);
            aa.x += __shfl_xor(aa.x, m); aa.y += __shfl_xor(aa.y, m);
            aa.z += __shfl_xor(aa.z, m); aa.w += __shfl_xor(aa.w, m);
            ab.x += __shfl_xor(ab.x, m); ab.y += __shfl_xor(ab.y, m);
            ab.z += __shfl_xor(ab.z, m); ab.w += __shfl_xor(ab.w, m);
        }
        float inv = 1.f / l;
        xa.x = aa.x * inv; xa.y = aa.y * inv; xa.z = aa.z * inv; xa.w = aa.w * inv;
        xb.x = ab.x * inv; xb.y = ab.y * inv; xb.z = ab.z * inv; xb.w = ab.w * inv;
    }
    // ---- final association: scores vs K (LDS), values from global V ----
    {
        const float4* vbase = (const float4*)(v + (size_t)bh * N_DIM * D_DIM);
        float4 sxa, sxb;
        sxa.x = C * xa.x; sxa.y = C * xa.y; sxa.z = C * xa.z; sxa.w = C * xa.w;
        sxb.x = C * xb.x; sxb.y = C * xb.y; sxb.z = C * xb.z; sxb.w = C * xb.w;
        float l = 0.f;
        float4 aa = {0, 0, 0, 0}, ab = {0, 0, 0, 0};
        #pragma unroll 4
        for (int jj = 0; jj < 128; ++jj) {
            int j = jj * 4 + jq;
            float4 ka = ((const float4*)Kl)[2 * j];
            float4 kb = ((const float4*)Kl)[2 * j + 1];
            float s = sxa.x * ka.x + sxa.y * ka.y + sxa.z * ka.z + sxa.w * ka.w
                    + sxb.x * kb.x + sxb.y * kb.y + sxb.z * kb.z + sxb.w * kb.w;
            float ee = __builtin_amdgcn_exp2f(s);
            l += ee;
            float4 va = vbase[2 * j];
            float4 vb = vbase[2 * j + 1];
            aa.x += ee * va.x; aa.y += ee * va.y; aa.z += ee * va.z; aa.w += ee * va.w;
            ab.x += ee * vb.x; ab.y += ee * vb.y; ab.z += ee * vb.z; ab.w += ee * vb.w;
        }
        #pragma unroll
        for (int m = 1; m <= 2; m <<= 1) {
            l    += __shfl_xor(l, m);
            aa.x += __shfl_xor(aa.x, m); aa.y += __shfl_xor(aa.y, m);
            aa.z += __shfl_xor(aa.z, m); aa.w += __shfl_xor(aa.w, m);
            ab.x += __shfl_xor(ab.x, m); ab.y += __shfl_xor(ab.y, m);
            ab.z += __shfl_xor(ab.z, m); ab.w += __shfl_xor(ab.w, m);
        }
        float inv = 1.f / l;
        if (jq == 0) {
            float4 oa, ob;
            oa.x = aa.x * inv; oa.y = aa.y * inv; oa.z = aa.z * inv; oa.w = aa.w * inv;
            ob.x = ab.x * inv; ob.y = ab.y * inv; ob.z = ab.z * inv; ob.w = ab.w * inv;
            ((float4*)qrow)[0] = oa;
            ((float4*)qrow)[1] = ob;
        }
    }
}

// ---------------------------------------------------------------------------
// K4: y[b] = bl + sum(partials) + dot(o_flat[b], Wl2)
// ---------------------------------------------------------------------------
__global__ __launch_bounds__(256) void finalize(const float* __restrict__ o,
                                                const float* __restrict__ Wl2,
                                                const float* __restrict__ partials,
                                                const float* __restrict__ bl,
                                                float* __restrict__ y) {
    const int b = blockIdx.x;
    const float* ob = o + (size_t)b * (H_DIM * N_DIM * D_DIM);
    float s = 0.f;
    for (int f = threadIdx.x; f < H_DIM * N_DIM * D_DIM; f += 256) s += ob[f] * Wl2[f];
    if (threadIdx.x < 64) s += partials[threadIdx.x];
    s = block_reduce_256(s);
    if (threadIdx.x == 0) y[b] = s + bl[0];
}

// ---------------------------------------------------------------------------
extern "C" void kernel_launch(void* const* d_in, const int* in_sizes, int n_in,
                              void* d_out, int out_size, void* d_ws, size_t ws_size,
                              hipStream_t stream) {
    const float* x   = (const float*)d_in[0];
    const float* g_q = (const float*)d_in[1];
    const float* b_q = (const float*)d_in[2];
    const float* g_k = (const float*)d_in[3];
    const float* b_k = (const float*)d_in[4];
    const float* g_v = (const float*)d_in[5];
    const float* b_v = (const float*)d_in[6];
    const float* Wq  = (const float*)d_in[7];
    const float* bq  = (const float*)d_in[8];
    const float* Wk  = (const float*)d_in[9];
    const float* bk  = (const float*)d_in[10];
    const float* Wv  = (const float*)d_in[11];
    const float* bv  = (const float*)d_in[12];
    const float* Wo  = (const float*)d_in[13];
    const float* bo  = (const float*)d_in[14];
    const float* Wl  = (const float*)d_in[15];
    const float* bl  = (const float*)d_in[16];
    float* out = (float*)d_out;

    float* ws = (float*)d_ws;
    float* Wt       = ws;                   // 98304
    float* b2       = ws + 98304;           // 192
    float* partials = ws + 98496;           // 64
    float* colsum   = ws + 98560;           // 192 (+pad)
    float* Wl2      = ws + 98816;           // 32768
    float* q_t      = ws + 131584;          // 1048576  [B][H][N][8]
    float* k_t      = q_t + 1048576;
    float* v_t      = k_t + 1048576;

    prep_wt <<<192, 256, 0, stream>>>(Wq, Wk, Wv, g_q, g_k, g_v, Wt, colsum);
    prep_b2 <<<192, 256, 0, stream>>>(Wq, Wk, Wv, b_q, b_k, b_v, bq, bk, bv, b2);
    prep_wl2<<<512, 64, 0, stream>>>(Wl, Wo, Wl2);
    prep_c0 <<<64, 256, 0, stream>>>(Wl, bo, partials);
    ln_qkv  <<<512, 256, 0, stream>>>(x, Wt, b2, colsum, q_t);
    hopfield<<<2048, 256, 0, stream>>>(q_t, k_t, v_t);
    finalize<<<32, 256, 0, stream>>>(q_t, Wl2, partials, bl, out);
}

// Round 5
// 292.113 us; speedup vs baseline: 5.2874x; 1.3578x over previous
//
#include <hip/hip_runtime.h>

#define E_DIM 512
#define N_DIM 512
#define B_DIM 32
#define H_DIM 8
#define D_DIM 8
#define P3    192   // 3 * H * D

typedef _Float16 half_t;
typedef __attribute__((ext_vector_type(4))) _Float16 half4v;
typedef __attribute__((ext_vector_type(8))) _Float16 half8v;
typedef __attribute__((ext_vector_type(4))) float f32x4;

// ---------------------------------------------------------------------------
__device__ inline float block_reduce_256(float v) {
    __shared__ float red[4];
    #pragma unroll
    for (int m = 32; m >= 1; m >>= 1) v += __shfl_xor(v, m);
    int w = threadIdx.x >> 6;
    if ((threadIdx.x & 63) == 0) red[w] = v;
    __syncthreads();
    if (threadIdx.x == 0) v = red[0] + red[1] + red[2] + red[3];
    return v;
}

__device__ inline half8v cvt8(float4 a, float4 b) {
    half8v h;
    h[0] = (half_t)a.x; h[1] = (half_t)a.y; h[2] = (half_t)a.z; h[3] = (half_t)a.w;
    h[4] = (half_t)b.x; h[5] = (half_t)b.y; h[6] = (half_t)b.z; h[7] = (half_t)b.w;
    return h;
}

// ---------------------------------------------------------------------------
// K0: fused prep. Wt[e][p'] = W[p][e]*g[e]; colsum[p'] = sum_e Wt;
// b2[p'] = bias[p] + dot(W[p,:], ln_beta). One block per p' (192).
// ---------------------------------------------------------------------------
__global__ __launch_bounds__(256) void prep_w(const float* __restrict__ Wq,
                        const float* __restrict__ Wk, const float* __restrict__ Wv,
                        const float* __restrict__ gq, const float* __restrict__ gk,
                        const float* __restrict__ gv,
                        const float* __restrict__ bnq, const float* __restrict__ bnk,
                        const float* __restrict__ bnv,
                        const float* __restrict__ bq, const float* __restrict__ bk,
                        const float* __restrict__ bv,
                        float* __restrict__ Wt, float* __restrict__ colsum,
                        float* __restrict__ b2) {
    int pp = blockIdx.x;     // 192
    int which = pp >> 6, p = pp & 63;
    const float* W  = (which == 0) ? Wq  : (which == 1) ? Wk  : Wv;
    const float* g  = (which == 0) ? gq  : (which == 1) ? gk  : gv;
    const float* bn = (which == 0) ? bnq : (which == 1) ? bnk : bnv;
    const float* bb = (which == 0) ? bq  : (which == 1) ? bk  : bv;
    int t = threadIdx.x;
    float cs = 0.f, dt = 0.f;
    #pragma unroll
    for (int l = 0; l < 2; ++l) {
        int e = t + l * 256;
        float wv = W[p * E_DIM + e];
        float wg = wv * g[e];
        Wt[e * P3 + pp] = wg;
        cs += wg;
        dt += wv * bn[e];
    }
    cs = block_reduce_256(cs);
    __syncthreads();
    dt = block_reduce_256(dt);
    if (t == 0) { colsum[pp] = cs; b2[pp] = dt + bb[p]; }
}

// ---------------------------------------------------------------------------
// K3: Wl2[h*4096+n*8+d] = sum_e Wl[n*512+e]*Wo[e*64+h*8+d]; also
// pc0[n] = dot(Wl[n,:], bo). One block per n (512 blocks, 64 threads).
// ---------------------------------------------------------------------------
__global__ __launch_bounds__(64) void prep_wl2c(const float* __restrict__ Wl,
                                                const float* __restrict__ Wo,
                                                const float* __restrict__ bo,
                                                float* __restrict__ Wl2,
                                                float* __restrict__ pc0) {
    __shared__ float row[E_DIM];
    int n = blockIdx.x, t = threadIdx.x;
    float pc = 0.f;
    #pragma unroll
    for (int l = 0; l < 8; ++l) {
        float rv = Wl[n * E_DIM + t + l * 64];
        row[t + l * 64] = rv;
        pc += rv * bo[t + l * 64];
    }
    __syncthreads();
    float s = 0.f;
    #pragma unroll 4
    for (int e = 0; e < E_DIM; ++e) s += row[e] * Wo[e * 64 + t];
    Wl2[(t >> 3) * (N_DIM * D_DIM) + n * D_DIM + (t & 7)] = s;
    #pragma unroll
    for (int m = 32; m >= 1; m >>= 1) pc += __shfl_xor(pc, m);
    if (t == 0) pc0[n] = pc;
}

// ---------------------------------------------------------------------------
// K1: fused LN + QKV projection, LDS-tiled GEMM, single pass over x.
// (unchanged from round 4)
// ---------------------------------------------------------------------------
__global__ __launch_bounds__(256, 4) void ln_qkv(const float* __restrict__ x,
                                                 const float* __restrict__ Wt,
                                                 const float* __restrict__ b2,
                                                 const float* __restrict__ colsum,
                                                 float* __restrict__ qkv) {
    __shared__ float At[32 * 32];
    __shared__ float Bt[32 * P3];
    __shared__ float stats[32][2];
    const int t = threadIdx.x;
    const int row0 = blockIdx.x * 32;
    const int tx = t & 63, rg = t >> 6;
    const int sr = t >> 3, sc = t & 7;
    float acc[8][3];
    #pragma unroll
    for (int kk = 0; kk < 8; ++kk) { acc[kk][0] = 0.f; acc[kk][1] = 0.f; acc[kk][2] = 0.f; }
    float sx = 0.f, sxx = 0.f;
    const float4* xrow = (const float4*)(x + (size_t)(row0 + sr) * E_DIM) + sc;

    for (int tile = 0; tile < 16; ++tile) {
        float4 av = xrow[tile * 8];
        sx  += av.x + av.y + av.z + av.w;
        sxx += av.x * av.x + av.y * av.y + av.z * av.z + av.w * av.w;
        ((float4*)At)[t] = av;
        const float4* bsrc = (const float4*)(Wt + (size_t)tile * 32 * P3);
        #pragma unroll
        for (int l = 0; l < 6; ++l) ((float4*)Bt)[t + l * 256] = bsrc[t + l * 256];
        __syncthreads();
        #pragma unroll 2
        for (int ee = 0; ee < 32; ee += 4) {
            float4 a[8];
            #pragma unroll
            for (int kk = 0; kk < 8; ++kk)
                a[kk] = *(const float4*)&At[(rg + 4 * kk) * 32 + ee];
            #pragma unroll
            for (int e2 = 0; e2 < 4; ++e2) {
                float w0 = Bt[(ee + e2) * P3 + tx];
                float w1 = Bt[(ee + e2) * P3 + tx + 64];
                float w2 = Bt[(ee + e2) * P3 + tx + 128];
                #pragma unroll
                for (int kk = 0; kk < 8; ++kk) {
                    float xv = (&a[kk].x)[e2];
                    acc[kk][0] += xv * w0;
                    acc[kk][1] += xv * w1;
                    acc[kk][2] += xv * w2;
                }
            }
        }
        __syncthreads();
    }
    #pragma unroll
    for (int m = 4; m >= 1; m >>= 1) { sx += __shfl_xor(sx, m); sxx += __shfl_xor(sxx, m); }
    if (sc == 0) {
        float mean = sx * (1.f / E_DIM);
        float var  = sxx * (1.f / E_DIM) - mean * mean;
        stats[sr][0] = mean;
        stats[sr][1] = rsqrtf(var + 1e-5f);
    }
    __syncthreads();
    float cs0 = colsum[tx], cs1 = colsum[tx + 64], cs2 = colsum[tx + 128];
    float bb0 = b2[tx],     bb1 = b2[tx + 64],     bb2 = b2[tx + 128];
    const size_t BHN8 = (size_t)B_DIM * H_DIM * N_DIM * D_DIM;
    const int h = tx >> 3, d = tx & 7;
    #pragma unroll
    for (int kk = 0; kk < 8; ++kk) {
        int r = rg + 4 * kk;
        float mean = stats[r][0], rs = stats[r][1];
        int ng = row0 + r;
        int b = ng >> 9, n = ng & 511;
        size_t base = (((size_t)(b * H_DIM + h)) * N_DIM + n) * D_DIM + d;
        qkv[base]            = rs * (acc[kk][0] - mean * cs0) + bb0;
        qkv[BHN8 + base]     = rs * (acc[kk][1] - mean * cs1) + bb1;
        qkv[2 * BHN8 + base] = rs * (acc[kk][2] - mean * cs2) + bb2;
    }
}

// ---------------------------------------------------------------------------
// K2: MFMA Hopfield. Block = 256 thr (4 waves); wave owns 32 rows (1 M-tile).
// Grid = 256 bh x 4 segs = 1024. All MFMAs are 16x16x32 f16 (HW-verified
// layouts). Per iteration per wave, per 32-j block:
//   S^T tiles: mfma(A=K rows [m=j], B=C*Xi rows [n=i])  -> exp2 -> P in
//   wave-private LDS (row-major [i][j], stride 36) ->
//   U += mfma(A=P, B=KT|ones)  (col 8 = softmax denominator).
// Iters 0-2 vs K; KTb rebuilt with V^T before iter 3. No barriers in the
// iteration loop (Xi rows wave-owned, K/KTb read-only).
// ---------------------------------------------------------------------------
__global__ __launch_bounds__(256) void hopfield(float* __restrict__ q,
                                                const float* __restrict__ k,
                                                const float* __restrict__ v) {
    __shared__ half_t Kb[N_DIM * 8];      // [j][d], 16B rows
    __shared__ half_t Xi[128 * 8];        // C-scaled xi, block-local rows
    __shared__ half_t KTb[16 * 536];      // rows 0-7 K^T/V^T, row 8 = 1, 9-15 = 0
    __shared__ half_t Pb[4 * 32 * 36];    // per-wave P scratch [i][j], stride 36
    const int t = threadIdx.x;
    const int lane = t & 63;
    const int w = t >> 6;
    const int g2 = lane >> 4;
    const int c16 = lane & 15;
    const int bh = blockIdx.x >> 2, seg = blockIdx.x & 3;
    const float C = 0.25f * 1.44269504088896f;   // beta * log2(e)
    const float* kg = k + (size_t)bh * (N_DIM * D_DIM);
    const float* vg = v + (size_t)bh * (N_DIM * D_DIM);
    float* qg = q + (size_t)bh * (N_DIM * D_DIM) + seg * 128 * 8;

    for (int i = t; i < 16 * 536; i += 256) KTb[i] = (half_t)0.f;
    __syncthreads();
    {   // stage K -> Kb rows + KTb transpose + ones row
        int j0 = 2 * t;
        float4 a0 = *(const float4*)(kg + j0 * 8);
        float4 a1 = *(const float4*)(kg + j0 * 8 + 4);
        float4 b0 = *(const float4*)(kg + j0 * 8 + 8);
        float4 b1 = *(const float4*)(kg + j0 * 8 + 12);
        half8v r0 = cvt8(a0, a1), r1 = cvt8(b0, b1);
        *(half8v*)&Kb[j0 * 8] = r0;
        *(half8v*)&Kb[j0 * 8 + 8] = r1;
        #pragma unroll
        for (int d = 0; d < 8; ++d) {
            KTb[d * 536 + j0] = r0[d];
            KTb[d * 536 + j0 + 1] = r1[d];
        }
        KTb[8 * 536 + j0] = (half_t)1.f;
        KTb[8 * 536 + j0 + 1] = (half_t)1.f;
    }
    if (t < 128) {   // stage Xi = C * q (my 128 rows)
        const float* qr = qg + t * 8;
        float4 a = *(const float4*)qr, b = *(const float4*)(qr + 4);
        half8v h;
        h[0] = (half_t)(C * a.x); h[1] = (half_t)(C * a.y);
        h[2] = (half_t)(C * a.z); h[3] = (half_t)(C * a.w);
        h[4] = (half_t)(C * b.x); h[5] = (half_t)(C * b.y);
        h[6] = (half_t)(C * b.z); h[7] = (half_t)(C * b.w);
        *(half8v*)&Xi[t * 8] = h;
    }
    __syncthreads();

    const half_t* zsrc = &KTb[9 * 536];   // 16 B of guaranteed zeros
    half_t* myP = &Pb[w * 32 * 36];

    for (int it = 0; it < 4; ++it) {
        if (it == 3) {   // swap KTb rows 0-7 to V^T
            __syncthreads();
            int j0 = 2 * t;
            float4 a0 = *(const float4*)(vg + j0 * 8);
            float4 a1 = *(const float4*)(vg + j0 * 8 + 4);
            float4 b0 = *(const float4*)(vg + j0 * 8 + 8);
            float4 b1 = *(const float4*)(vg + j0 * 8 + 12);
            half8v r0 = cvt8(a0, a1), r1 = cvt8(b0, b1);
            #pragma unroll
            for (int d = 0; d < 8; ++d) {
                KTb[d * 536 + j0] = r0[d];
                KTb[d * 536 + j0 + 1] = r1[d];
            }
            __syncthreads();
        }
        const half_t* x0p = (g2 == 0) ? &Xi[(w * 32 + c16) * 8] : zsrc;
        const half_t* x1p = (g2 == 0) ? &Xi[(w * 32 + 16 + c16) * 8] : zsrc;
        half8v bxi0 = *(const half8v*)x0p;
        half8v bxi1 = *(const half8v*)x1p;
        f32x4 U0 = {0.f, 0.f, 0.f, 0.f}, U1 = {0.f, 0.f, 0.f, 0.f};
        for (int j32 = 0; j32 < 16; ++j32) {
            #pragma unroll
            for (int hh = 0; hh < 2; ++hh) {
                int jt16 = j32 * 2 + hh;
                const half_t* akp = (g2 == 0) ? &Kb[(jt16 * 16 + c16) * 8] : zsrc;
                half8v ak = *(const half8v*)akp;
                f32x4 S0 = {0.f, 0.f, 0.f, 0.f}, S1 = {0.f, 0.f, 0.f, 0.f};
                S0 = __builtin_amdgcn_mfma_f32_16x16x32_f16(ak, bxi0, S0, 0, 0, 0);
                S1 = __builtin_amdgcn_mfma_f32_16x16x32_f16(ak, bxi1, S1, 0, 0, 0);
                half4v p0, p1;
                #pragma unroll
                for (int r = 0; r < 4; ++r) {
                    p0[r] = (half_t)__builtin_amdgcn_exp2f(S0[r]);
                    p1[r] = (half_t)__builtin_amdgcn_exp2f(S1[r]);
                }
                int joff = hh * 16 + g2 * 4;
                *(half4v*)&myP[c16 * 36 + joff] = p0;
                *(half4v*)&myP[(16 + c16) * 36 + joff] = p1;
            }
            half4v alo0 = *(const half4v*)&myP[c16 * 36 + g2 * 8];
            half4v ahi0 = *(const half4v*)&myP[c16 * 36 + g2 * 8 + 4];
            half4v alo1 = *(const half4v*)&myP[(16 + c16) * 36 + g2 * 8];
            half4v ahi1 = *(const half4v*)&myP[(16 + c16) * 36 + g2 * 8 + 4];
            half8v ap0 = __builtin_shufflevector(alo0, ahi0, 0, 1, 2, 3, 4, 5, 6, 7);
            half8v ap1 = __builtin_shufflevector(alo1, ahi1, 0, 1, 2, 3, 4, 5, 6, 7);
            half8v b2f = *(const half8v*)&KTb[c16 * 536 + j32 * 32 + g2 * 8];
            U0 = __builtin_amdgcn_mfma_f32_16x16x32_f16(ap0, b2f, U0, 0, 0, 0);
            U1 = __builtin_amdgcn_mfma_f32_16x16x32_f16(ap1, b2f, U1, 0, 0, 0);
        }
        int srcl = (lane & 48) | 8;   // lane holding col 8 (= l_i) of my row group
        #pragma unroll
        for (int r = 0; r < 4; ++r) {
            float l0 = __shfl(U0[r], srcl, 64);
            float l1 = __shfl(U1[r], srcl, 64);
            if (c16 < 8) {
                int i0 = w * 32 + g2 * 4 + r;
                int i1 = i0 + 16;
                if (it < 3) {
                    Xi[i0 * 8 + c16] = (half_t)(U0[r] * (C / l0));
                    Xi[i1 * 8 + c16] = (half_t)(U1[r] * (C / l1));
                } else {
                    qg[i0 * 8 + c16] = U0[r] / l0;
                    qg[i1 * 8 + c16] = U1[r] / l1;
                }
            }
        }
    }
}

// ---------------------------------------------------------------------------
// K4: y[b] = bl + sum(pc0) + dot(o_flat[b], Wl2)
// ---------------------------------------------------------------------------
__global__ __launch_bounds__(256) void finalize(const float* __restrict__ o,
                                                const float* __restrict__ Wl2,
                                                const float* __restrict__ pc0,
                                                const float* __restrict__ bl,
                                                float* __restrict__ y) {
    const int b = blockIdx.x;
    const float* ob = o + (size_t)b * (H_DIM * N_DIM * D_DIM);
    float s = 0.f;
    for (int f = threadIdx.x; f < H_DIM * N_DIM * D_DIM; f += 256) s += ob[f] * Wl2[f];
    s += pc0[threadIdx.x] + pc0[threadIdx.x + 256];
    s = block_reduce_256(s);
    if (threadIdx.x == 0) y[b] = s + bl[0];
}

// ---------------------------------------------------------------------------
extern "C" void kernel_launch(void* const* d_in, const int* in_sizes, int n_in,
                              void* d_out, int out_size, void* d_ws, size_t ws_size,
                              hipStream_t stream) {
    const float* x   = (const float*)d_in[0];
    const float* g_q = (const float*)d_in[1];
    const float* b_q = (const float*)d_in[2];
    const float* g_k = (const float*)d_in[3];
    const float* b_k = (const float*)d_in[4];
    const float* g_v = (const float*)d_in[5];
    const float* b_v = (const float*)d_in[6];
    const float* Wq  = (const float*)d_in[7];
    const float* bq  = (const float*)d_in[8];
    const float* Wk  = (const float*)d_in[9];
    const float* bk  = (const float*)d_in[10];
    const float* Wv  = (const float*)d_in[11];
    const float* bv  = (const float*)d_in[12];
    const float* Wo  = (const float*)d_in[13];
    const float* bo  = (const float*)d_in[14];
    const float* Wl  = (const float*)d_in[15];
    const float* bl  = (const float*)d_in[16];
    float* out = (float*)d_out;

    float* ws = (float*)d_ws;
    float* Wt     = ws;                     // 98304
    float* b2     = ws + 98304;             // 192
    float* colsum = ws + 98496;             // 192
    float* pc0    = ws + 98688;             // 512
    float* Wl2    = ws + 99200;             // 32768
    float* q_t    = ws + 131968;            // 1048576  [B][H][N][8]
    float* k_t    = q_t + 1048576;
    float* v_t    = k_t + 1048576;

    prep_w  <<<192, 256, 0, stream>>>(Wq, Wk, Wv, g_q, g_k, g_v,
                                      b_q, b_k, b_v, bq, bk, bv, Wt, colsum, b2);
    prep_wl2c<<<512, 64, 0, stream>>>(Wl, Wo, bo, Wl2, pc0);
    ln_qkv  <<<512, 256, 0, stream>>>(x, Wt, b2, colsum, q_t);
    hopfield<<<1024, 256, 0, stream>>>(q_t, k_t, v_t);
    finalize<<<32, 256, 0, stream>>>(q_t, Wl2, pc0, bl, out);
}

// Round 6
// 221.554 us; speedup vs baseline: 6.9712x; 1.3185x over previous
//
#include <hip/hip_runtime.h>

#define E_DIM 512
#define N_DIM 512
#define B_DIM 32
#define H_DIM 8
#define D_DIM 8
#define P3    192   // 3 * H * D

typedef _Float16 half_t;
typedef __attribute__((ext_vector_type(4))) _Float16 half4v;
typedef __attribute__((ext_vector_type(8))) _Float16 half8v;
typedef __attribute__((ext_vector_type(4))) float f32x4;

// ---------------------------------------------------------------------------
__device__ inline float block_reduce_256(float v) {
    __shared__ float red[4];
    #pragma unroll
    for (int m = 32; m >= 1; m >>= 1) v += __shfl_xor(v, m);
    int w = threadIdx.x >> 6;
    if ((threadIdx.x & 63) == 0) red[w] = v;
    __syncthreads();
    if (threadIdx.x == 0) v = red[0] + red[1] + red[2] + red[3];
    return v;
}

__device__ inline half8v cvt8(float4 a, float4 b) {
    half8v h;
    h[0] = (half_t)a.x; h[1] = (half_t)a.y; h[2] = (half_t)a.z; h[3] = (half_t)a.w;
    h[4] = (half_t)b.x; h[5] = (half_t)b.y; h[6] = (half_t)b.z; h[7] = (half_t)b.w;
    return h;
}

// ---------------------------------------------------------------------------
// K0: prep. Wth[p'][e] = f16(W[p][e]*g[e]); colsum[p'] = sum_e f16-rounded w;
// b2[p'] = bias[p] + dot(W[p,:], ln_beta). One block per p' (192).
// ---------------------------------------------------------------------------
__global__ __launch_bounds__(256) void prep_w(const float* __restrict__ Wq,
                        const float* __restrict__ Wk, const float* __restrict__ Wv,
                        const float* __restrict__ gq, const float* __restrict__ gk,
                        const float* __restrict__ gv,
                        const float* __restrict__ bnq, const float* __restrict__ bnk,
                        const float* __restrict__ bnv,
                        const float* __restrict__ bq, const float* __restrict__ bk,
                        const float* __restrict__ bv,
                        half_t* __restrict__ Wth, float* __restrict__ colsum,
                        float* __restrict__ b2) {
    int pp = blockIdx.x;     // 192
    int which = pp >> 6, p = pp & 63;
    const float* W  = (which == 0) ? Wq  : (which == 1) ? Wk  : Wv;
    const float* g  = (which == 0) ? gq  : (which == 1) ? gk  : gv;
    const float* bn = (which == 0) ? bnq : (which == 1) ? bnk : bnv;
    const float* bb = (which == 0) ? bq  : (which == 1) ? bk  : bv;
    int t = threadIdx.x;
    float cs = 0.f, dt = 0.f;
    #pragma unroll
    for (int l = 0; l < 2; ++l) {
        int e = t + l * 256;
        float wv = W[p * E_DIM + e];
        half_t wh = (half_t)(wv * g[e]);
        Wth[(size_t)pp * E_DIM + e] = wh;
        cs += (float)wh;            // colsum of the f16-rounded weights
        dt += wv * bn[e];
    }
    cs = block_reduce_256(cs);
    __syncthreads();
    dt = block_reduce_256(dt);
    if (t == 0) { colsum[pp] = cs; b2[pp] = dt + bb[p]; }
}

// ---------------------------------------------------------------------------
// K3: Wl2[h*4096+n*8+d] = sum_e Wl[n*512+e]*Wo[e*64+h*8+d]; also
// pc0[n] = dot(Wl[n,:], bo). One block per n (512 blocks, 64 threads).
// ---------------------------------------------------------------------------
__global__ __launch_bounds__(64) void prep_wl2c(const float* __restrict__ Wl,
                                                const float* __restrict__ Wo,
                                                const float* __restrict__ bo,
                                                float* __restrict__ Wl2,
                                                float* __restrict__ pc0) {
    __shared__ float row[E_DIM];
    int n = blockIdx.x, t = threadIdx.x;
    float pc = 0.f;
    #pragma unroll
    for (int l = 0; l < 8; ++l) {
        float rv = Wl[n * E_DIM + t + l * 64];
        row[t + l * 64] = rv;
        pc += rv * bo[t + l * 64];
    }
    __syncthreads();
    float s = 0.f;
    #pragma unroll 4
    for (int e = 0; e < E_DIM; ++e) s += row[e] * Wo[e * 64 + t];
    Wl2[(t >> 3) * (N_DIM * D_DIM) + n * D_DIM + (t & 7)] = s;
    #pragma unroll
    for (int m = 32; m >= 1; m >>= 1) pc += __shfl_xor(pc, m);
    if (t == 0) pc0[n] = pc;
}

// ---------------------------------------------------------------------------
// K1: fused LN + QKV projection — pure-MFMA, ZERO LDS, zero barriers.
// Block = 256 thr = 4 waves, 1 M-tile (16 rows). Wave w owns p' cols
// [w*48, w*48+48) = 3 N-tiles. A-frags straight from global x (f32->f16),
// B-frags from global Wth (L1/L2-resident, 192 KB). LN stats in registers:
// lane accumulates its A elements; shfl_xor(16,32) gives row sums (row =
// lane&15); epilogue shfls stats for D rows g2*4+r. LN applied as
//   out = rs*(acc_raw - mean*colsum) + b2   (round-4 identity).
// Output: f16 qkv [which][B][H][N][8]. Grid 1024 -> 32 waves/CU.
// ---------------------------------------------------------------------------
__global__ __launch_bounds__(256) void ln_qkv(const float* __restrict__ x,
                                              const half_t* __restrict__ Wth,
                                              const float* __restrict__ b2,
                                              const float* __restrict__ colsum,
                                              half_t* __restrict__ qkv16) {
    const int t = threadIdx.x;
    const int lane = t & 63;
    const int w = t >> 6;                 // wave = N-quarter
    const int g2 = lane >> 4, c16 = lane & 15;
    const int row0 = blockIdx.x * 16;
    const float*  xr    = x + (size_t)(row0 + c16) * E_DIM;
    const half_t* wbase = Wth + (size_t)(w * 48 + c16) * E_DIM;
    f32x4 acc[3] = {{0.f,0.f,0.f,0.f},{0.f,0.f,0.f,0.f},{0.f,0.f,0.f,0.f}};
    float sx = 0.f, sxx = 0.f;

    #pragma unroll 2
    for (int tile = 0; tile < 8; ++tile) {
        #pragma unroll
        for (int kk = 0; kk < 2; ++kk) {
            int k = tile * 64 + kk * 32 + g2 * 8;
            float4 a0 = *(const float4*)(xr + k);
            float4 a1 = *(const float4*)(xr + k + 4);
            sx  += a0.x + a0.y + a0.z + a0.w + a1.x + a1.y + a1.z + a1.w;
            sxx += a0.x*a0.x + a0.y*a0.y + a0.z*a0.z + a0.w*a0.w
                 + a1.x*a1.x + a1.y*a1.y + a1.z*a1.z + a1.w*a1.w;
            half8v af = cvt8(a0, a1);
            #pragma unroll
            for (int nt = 0; nt < 3; ++nt) {
                half8v bf = *(const half8v*)(wbase + (size_t)nt * 16 * E_DIM + k);
                acc[nt] = __builtin_amdgcn_mfma_f32_16x16x32_f16(af, bf, acc[nt], 0, 0, 0);
            }
        }
    }
    // row stats: lane's partial covers 1/4 of row (lane&15); combine g2 groups
    sx  += __shfl_xor(sx, 16);  sx  += __shfl_xor(sx, 32);
    sxx += __shfl_xor(sxx, 16); sxx += __shfl_xor(sxx, 32);
    float mean = sx * (1.f / E_DIM);
    float var  = sxx * (1.f / E_DIM) - mean * mean;
    float rs   = rsqrtf(var + 1e-5f);
    // epilogue: D[m][n] m=row=g2*4+r, n=col=c16
    #pragma unroll
    for (int nt = 0; nt < 3; ++nt) {
        int pp = w * 48 + nt * 16 + c16;
        float cs = colsum[pp], bb = b2[pp];
        int which = pp >> 6, p = pp & 63;
        int h = p >> 3, d = p & 7;
        half_t* dst0 = qkv16 + (size_t)which * (B_DIM * H_DIM * N_DIM * D_DIM);
        #pragma unroll
        for (int r = 0; r < 4; ++r) {
            int rowi = g2 * 4 + r;
            float m_r  = __shfl(mean, rowi);
            float rs_r = __shfl(rs, rowi);
            float val = rs_r * (acc[nt][r] - m_r * cs) + bb;
            int ng = row0 + rowi;
            int b = ng >> 9, n = ng & 511;
            dst0[(((size_t)(b * H_DIM + h)) * N_DIM + n) * D_DIM + d] = (half_t)val;
        }
    }
}

// ---------------------------------------------------------------------------
// K2: MFMA Hopfield (f16 in, f32 o out). Same structure as round 5 (passed),
// inputs now f16 so staging drops the f32 loads/cvt.
// ---------------------------------------------------------------------------
__global__ __launch_bounds__(256) void hopfield(const half_t* __restrict__ q16,
                                                const half_t* __restrict__ k16,
                                                const half_t* __restrict__ v16,
                                                float* __restrict__ o) {
    __shared__ half_t Kb[N_DIM * 8];      // [j][d]
    __shared__ half_t Xi[128 * 8];        // C-scaled xi
    __shared__ half_t KTb[16 * 536];      // rows 0-7 K^T/V^T, row 8 = 1, 9-15 = 0
    __shared__ half_t Pb[4 * 32 * 36];    // per-wave P scratch
    const int t = threadIdx.x;
    const int lane = t & 63;
    const int w = t >> 6;
    const int g2 = lane >> 4;
    const int c16 = lane & 15;
    const int bh = blockIdx.x >> 2, seg = blockIdx.x & 3;
    const float C = 0.25f * 1.44269504088896f;
    const half_t* kg = k16 + (size_t)bh * (N_DIM * D_DIM);
    const half_t* vg = v16 + (size_t)bh * (N_DIM * D_DIM);
    const half_t* qg = q16 + (size_t)bh * (N_DIM * D_DIM) + seg * 128 * 8;
    float* og = o + (size_t)bh * (N_DIM * D_DIM) + seg * 128 * 8;

    for (int i = t; i < 16 * 536; i += 256) KTb[i] = (half_t)0.f;
    __syncthreads();
    {   // stage K rows + K^T + ones row
        int j0 = 2 * t;
        half8v r0 = *(const half8v*)(kg + j0 * 8);
        half8v r1 = *(const half8v*)(kg + j0 * 8 + 8);
        *(half8v*)&Kb[j0 * 8] = r0;
        *(half8v*)&Kb[j0 * 8 + 8] = r1;
        #pragma unroll
        for (int d = 0; d < 8; ++d) {
            KTb[d * 536 + j0] = r0[d];
            KTb[d * 536 + j0 + 1] = r1[d];
        }
        KTb[8 * 536 + j0] = (half_t)1.f;
        KTb[8 * 536 + j0 + 1] = (half_t)1.f;
    }
    if (t < 128) {   // stage Xi = C * q
        half8v hq = *(const half8v*)(qg + t * 8);
        half8v h;
        #pragma unroll
        for (int d = 0; d < 8; ++d) h[d] = (half_t)(C * (float)hq[d]);
        *(half8v*)&Xi[t * 8] = h;
    }
    __syncthreads();

    const half_t* zsrc = &KTb[9 * 536];
    half_t* myP = &Pb[w * 32 * 36];

    for (int it = 0; it < 4; ++it) {
        if (it == 3) {   // swap KTb rows 0-7 to V^T
            __syncthreads();
            int j0 = 2 * t;
            half8v r0 = *(const half8v*)(vg + j0 * 8);
            half8v r1 = *(const half8v*)(vg + j0 * 8 + 8);
            #pragma unroll
            for (int d = 0; d < 8; ++d) {
                KTb[d * 536 + j0] = r0[d];
                KTb[d * 536 + j0 + 1] = r1[d];
            }
            __syncthreads();
        }
        const half_t* x0p = (g2 == 0) ? &Xi[(w * 32 + c16) * 8] : zsrc;
        const half_t* x1p = (g2 == 0) ? &Xi[(w * 32 + 16 + c16) * 8] : zsrc;
        half8v bxi0 = *(const half8v*)x0p;
        half8v bxi1 = *(const half8v*)x1p;
        f32x4 U0 = {0.f, 0.f, 0.f, 0.f}, U1 = {0.f, 0.f, 0.f, 0.f};
        for (int j32 = 0; j32 < 16; ++j32) {
            #pragma unroll
            for (int hh = 0; hh < 2; ++hh) {
                int jt16 = j32 * 2 + hh;
                const half_t* akp = (g2 == 0) ? &Kb[(jt16 * 16 + c16) * 8] : zsrc;
                half8v ak = *(const half8v*)akp;
                f32x4 S0 = {0.f, 0.f, 0.f, 0.f}, S1 = {0.f, 0.f, 0.f, 0.f};
                S0 = __builtin_amdgcn_mfma_f32_16x16x32_f16(ak, bxi0, S0, 0, 0, 0);
                S1 = __builtin_amdgcn_mfma_f32_16x16x32_f16(ak, bxi1, S1, 0, 0, 0);
                half4v p0, p1;
                #pragma unroll
                for (int r = 0; r < 4; ++r) {
                    p0[r] = (half_t)__builtin_amdgcn_exp2f(S0[r]);
                    p1[r] = (half_t)__builtin_amdgcn_exp2f(S1[r]);
                }
                int joff = hh * 16 + g2 * 4;
                *(half4v*)&myP[c16 * 36 + joff] = p0;
                *(half4v*)&myP[(16 + c16) * 36 + joff] = p1;
            }
            half4v alo0 = *(const half4v*)&myP[c16 * 36 + g2 * 8];
            half4v ahi0 = *(const half4v*)&myP[c16 * 36 + g2 * 8 + 4];
            half4v alo1 = *(const half4v*)&myP[(16 + c16) * 36 + g2 * 8];
            half4v ahi1 = *(const half4v*)&myP[(16 + c16) * 36 + g2 * 8 + 4];
            half8v ap0 = __builtin_shufflevector(alo0, ahi0, 0, 1, 2, 3, 4, 5, 6, 7);
            half8v ap1 = __builtin_shufflevector(alo1, ahi1, 0, 1, 2, 3, 4, 5, 6, 7);
            half8v b2f = *(const half8v*)&KTb[c16 * 536 + j32 * 32 + g2 * 8];
            U0 = __builtin_amdgcn_mfma_f32_16x16x32_f16(ap0, b2f, U0, 0, 0, 0);
            U1 = __builtin_amdgcn_mfma_f32_16x16x32_f16(ap1, b2f, U1, 0, 0, 0);
        }
        int srcl = (lane & 48) | 8;
        #pragma unroll
        for (int r = 0; r < 4; ++r) {
            float l0 = __shfl(U0[r], srcl, 64);
            float l1 = __shfl(U1[r], srcl, 64);
            if (c16 < 8) {
                int i0 = w * 32 + g2 * 4 + r;
                int i1 = i0 + 16;
                if (it < 3) {
                    Xi[i0 * 8 + c16] = (half_t)(U0[r] * (C / l0));
                    Xi[i1 * 8 + c16] = (half_t)(U1[r] * (C / l1));
                } else {
                    og[i0 * 8 + c16] = U0[r] / l0;
                    og[i1 * 8 + c16] = U1[r] / l1;
                }
            }
        }
    }
}

// ---------------------------------------------------------------------------
// K4a: partial[b*8+chunk] = dot(o[b][chunk*4096:+4096], Wl2[chunk*4096:+4096])
// ---------------------------------------------------------------------------
__global__ __launch_bounds__(256) void finalize1(const float* __restrict__ o,
                                                 const float* __restrict__ Wl2,
                                                 float* __restrict__ partial) {
    const int bc = blockIdx.x;              // 256 = 32 b x 8 chunks
    const int b = bc >> 3, chunk = bc & 7;
    const float4* ob = (const float4*)(o + (size_t)b * 32768 + chunk * 4096);
    const float4* wl = (const float4*)(Wl2 + chunk * 4096);
    float s = 0.f;
    #pragma unroll
    for (int l = 0; l < 4; ++l) {
        float4 a = ob[threadIdx.x + l * 256];
        float4 w = wl[threadIdx.x + l * 256];
        s += a.x * w.x + a.y * w.y + a.z * w.z + a.w * w.w;
    }
    s = block_reduce_256(s);
    if (threadIdx.x == 0) partial[bc] = s;
}

// K4b: y[b] = bl + sum(pc0) + sum_c partial[b*8+c]
__global__ __launch_bounds__(256) void finalize2(const float* __restrict__ partial,
                                                 const float* __restrict__ pc0,
                                                 const float* __restrict__ bl,
                                                 float* __restrict__ y) {
    __shared__ float c0s;
    int t = threadIdx.x;
    float s2 = pc0[t] + pc0[t + 256];
    s2 = block_reduce_256(s2);
    if (t == 0) c0s = s2 + bl[0];
    __syncthreads();
    if (t < 32) {
        float s = 0.f;
        #pragma unroll
        for (int c = 0; c < 8; ++c) s += partial[t * 8 + c];
        y[t] = s + c0s;
    }
}

// ---------------------------------------------------------------------------
extern "C" void kernel_launch(void* const* d_in, const int* in_sizes, int n_in,
                              void* d_out, int out_size, void* d_ws, size_t ws_size,
                              hipStream_t stream) {
    const float* x   = (const float*)d_in[0];
    const float* g_q = (const float*)d_in[1];
    const float* b_q = (const float*)d_in[2];
    const float* g_k = (const float*)d_in[3];
    const float* b_k = (const float*)d_in[4];
    const float* g_v = (const float*)d_in[5];
    const float* b_v = (const float*)d_in[6];
    const float* Wq  = (const float*)d_in[7];
    const float* bq  = (const float*)d_in[8];
    const float* Wk  = (const float*)d_in[9];
    const float* bk  = (const float*)d_in[10];
    const float* Wv  = (const float*)d_in[11];
    const float* bv  = (const float*)d_in[12];
    const float* Wo  = (const float*)d_in[13];
    const float* bo  = (const float*)d_in[14];
    const float* Wl  = (const float*)d_in[15];
    const float* bl  = (const float*)d_in[16];
    float* out = (float*)d_out;

    float* ws = (float*)d_ws;
    float*  colsum  = ws;                     // 192
    float*  b2      = ws + 192;               // 192
    float*  pc0     = ws + 384;               // 512
    float*  partial = ws + 896;               // 256
    float*  Wl2     = ws + 1152;              // 32768
    half_t* Wth     = (half_t*)(ws + 33920);  // 98304 halves  = 49152 floats
    half_t* qkv16   = (half_t*)(ws + 83072);  // 3*1048576 halves = 1572864 floats
    float*  o_t     = ws + 1655936;           // 1048576 floats

    half_t* q16 = qkv16;
    half_t* k16 = qkv16 + 1048576;
    half_t* v16 = qkv16 + 2097152;

    prep_w   <<<192, 256, 0, stream>>>(Wq, Wk, Wv, g_q, g_k, g_v,
                                       b_q, b_k, b_v, bq, bk, bv, Wth, colsum, b2);
    prep_wl2c<<<512, 64, 0, stream>>>(Wl, Wo, bo, Wl2, pc0);
    ln_qkv   <<<1024, 256, 0, stream>>>(x, Wth, b2, colsum, qkv16);
    hopfield <<<1024, 256, 0, stream>>>(q16, k16, v16, o_t);
    finalize1<<<256, 256, 0, stream>>>(o_t, Wl2, partial);
    finalize2<<<1, 256, 0, stream>>>(partial, pc0, bl, out);
}

// Round 7
// 189.755 us; speedup vs baseline: 8.1395x; 1.1676x over previous
//
#include <hip/hip_runtime.h>

#define E_DIM 512
#define N_DIM 512
#define B_DIM 32
#define H_DIM 8
#define D_DIM 8
#define P3    192   // 3 * H * D

typedef _Float16 half_t;
typedef __attribute__((ext_vector_type(4))) _Float16 half4v;
typedef __attribute__((ext_vector_type(8))) _Float16 half8v;
typedef __attribute__((ext_vector_type(4))) float f32x4;

#define PB_STRIDE 44   // halves; 22 dwords -> all LDS collisions <=2-way (free)

// ---------------------------------------------------------------------------
__device__ inline float block_reduce_256(float v) {
    __shared__ float red[4];
    #pragma unroll
    for (int m = 32; m >= 1; m >>= 1) v += __shfl_xor(v, m);
    int w = threadIdx.x >> 6;
    if ((threadIdx.x & 63) == 0) red[w] = v;
    __syncthreads();
    if (threadIdx.x == 0) v = red[0] + red[1] + red[2] + red[3];
    return v;
}

__device__ inline half8v cvt8(float4 a, float4 b) {
    half8v h;
    h[0] = (half_t)a.x; h[1] = (half_t)a.y; h[2] = (half_t)a.z; h[3] = (half_t)a.w;
    h[4] = (half_t)b.x; h[5] = (half_t)b.y; h[6] = (half_t)b.z; h[7] = (half_t)b.w;
    return h;
}

// ---------------------------------------------------------------------------
// K0: prep. Wth[p'][e] = f16(W[p][e]*g[e]); colsum[p'] = sum of f16-rounded w;
// b2[p'] = bias[p] + dot(W[p,:], ln_beta). Block 0 also inits y[b]=bl and
// c0acc=0 (y/ws are re-poisoned before every timed launch).
// ---------------------------------------------------------------------------
__global__ __launch_bounds__(256) void prep_w(const float* __restrict__ Wq,
                        const float* __restrict__ Wk, const float* __restrict__ Wv,
                        const float* __restrict__ gq, const float* __restrict__ gk,
                        const float* __restrict__ gv,
                        const float* __restrict__ bnq, const float* __restrict__ bnk,
                        const float* __restrict__ bnv,
                        const float* __restrict__ bq, const float* __restrict__ bk,
                        const float* __restrict__ bv,
                        const float* __restrict__ bl,
                        half_t* __restrict__ Wth, float* __restrict__ colsum,
                        float* __restrict__ b2, float* __restrict__ y,
                        float* __restrict__ c0acc) {
    int pp = blockIdx.x;     // 192
    int which = pp >> 6, p = pp & 63;
    const float* W  = (which == 0) ? Wq  : (which == 1) ? Wk  : Wv;
    const float* g  = (which == 0) ? gq  : (which == 1) ? gk  : gv;
    const float* bn = (which == 0) ? bnq : (which == 1) ? bnk : bnv;
    const float* bb = (which == 0) ? bq  : (which == 1) ? bk  : bv;
    int t = threadIdx.x;
    if (pp == 0) {
        if (t < 32) y[t] = bl[0];
        if (t == 32) c0acc[0] = 0.f;
    }
    float cs = 0.f, dt = 0.f;
    #pragma unroll
    for (int l = 0; l < 2; ++l) {
        int e = t + l * 256;
        float wv = W[p * E_DIM + e];
        half_t wh = (half_t)(wv * g[e]);
        Wth[(size_t)pp * E_DIM + e] = wh;
        cs += (float)wh;
        dt += wv * bn[e];
    }
    cs = block_reduce_256(cs);
    __syncthreads();
    dt = block_reduce_256(dt);
    if (t == 0) { colsum[pp] = cs; b2[pp] = dt + bb[p]; }
}

// ---------------------------------------------------------------------------
// K1: fused LN+QKV (blocks 0-1023, zero-LDS MFMA, unchanged math) AND
// Wl2 prep (blocks 1024-1535): Wl2[h*4096+n*8+d] = sum_e Wl[n,e]*Wo[e,h*8+d],
// 4 waves split e (4x latency hiding vs old 64-thread version); pc =
// dot(Wl[n,:], bo) atomically accumulated into c0acc.
// ---------------------------------------------------------------------------
__global__ __launch_bounds__(256) void ln_qkv_wl2(const float* __restrict__ x,
                                              const half_t* __restrict__ Wth,
                                              const float* __restrict__ b2,
                                              const float* __restrict__ colsum,
                                              half_t* __restrict__ qkv16,
                                              const float* __restrict__ Wl,
                                              const float* __restrict__ Wo,
                                              const float* __restrict__ bo,
                                              float* __restrict__ Wl2,
                                              float* __restrict__ c0acc) {
    if (blockIdx.x < 1024) {
        const int t = threadIdx.x;
        const int lane = t & 63;
        const int w = t >> 6;
        const int g2 = lane >> 4, c16 = lane & 15;
        const int row0 = blockIdx.x * 16;
        const float*  xr    = x + (size_t)(row0 + c16) * E_DIM;
        const half_t* wbase = Wth + (size_t)(w * 48 + c16) * E_DIM;
        f32x4 acc[3] = {{0.f,0.f,0.f,0.f},{0.f,0.f,0.f,0.f},{0.f,0.f,0.f,0.f}};
        float sx = 0.f, sxx = 0.f;
        #pragma unroll 2
        for (int tile = 0; tile < 8; ++tile) {
            #pragma unroll
            for (int kk = 0; kk < 2; ++kk) {
                int k = tile * 64 + kk * 32 + g2 * 8;
                float4 a0 = *(const float4*)(xr + k);
                float4 a1 = *(const float4*)(xr + k + 4);
                sx  += a0.x + a0.y + a0.z + a0.w + a1.x + a1.y + a1.z + a1.w;
                sxx += a0.x*a0.x + a0.y*a0.y + a0.z*a0.z + a0.w*a0.w
                     + a1.x*a1.x + a1.y*a1.y + a1.z*a1.z + a1.w*a1.w;
                half8v af = cvt8(a0, a1);
                #pragma unroll
                for (int nt = 0; nt < 3; ++nt) {
                    half8v bf = *(const half8v*)(wbase + (size_t)nt * 16 * E_DIM + k);
                    acc[nt] = __builtin_amdgcn_mfma_f32_16x16x32_f16(af, bf, acc[nt], 0, 0, 0);
                }
            }
        }
        sx  += __shfl_xor(sx, 16);  sx  += __shfl_xor(sx, 32);
        sxx += __shfl_xor(sxx, 16); sxx += __shfl_xor(sxx, 32);
        float mean = sx * (1.f / E_DIM);
        float var  = sxx * (1.f / E_DIM) - mean * mean;
        float rs   = rsqrtf(var + 1e-5f);
        #pragma unroll
        for (int nt = 0; nt < 3; ++nt) {
            int pp = w * 48 + nt * 16 + c16;
            float cs = colsum[pp], bb = b2[pp];
            int which = pp >> 6, p = pp & 63;
            int h = p >> 3, d = p & 7;
            half_t* dst0 = qkv16 + (size_t)which * (B_DIM * H_DIM * N_DIM * D_DIM);
            #pragma unroll
            for (int r = 0; r < 4; ++r) {
                int rowi = g2 * 4 + r;
                float m_r  = __shfl(mean, rowi);
                float rs_r = __shfl(rs, rowi);
                float val = rs_r * (acc[nt][r] - m_r * cs) + bb;
                int ng = row0 + rowi;
                int b = ng >> 9, n = ng & 511;
                dst0[(((size_t)(b * H_DIM + h)) * N_DIM + n) * D_DIM + d] = (half_t)val;
            }
        }
    } else {
        // ---- Wl2 prep: one block per n ----
        __shared__ float rowS[E_DIM];
        __shared__ float partS[4][64];
        const int n = blockIdx.x - 1024;
        const int t = threadIdx.x;
        float r0 = Wl[(size_t)n * E_DIM + t];
        float r1 = Wl[(size_t)n * E_DIM + t + 256];
        rowS[t] = r0; rowS[t + 256] = r1;
        float pc = r0 * bo[t] + r1 * bo[t + 256];
        pc = block_reduce_256(pc);           // syncthreads inside covers rowS
        if (t == 0) atomicAdd(c0acc, pc);
        const int w = t >> 6, lane = t & 63;
        float s = 0.f;
        #pragma unroll 4
        for (int e = w * 128; e < w * 128 + 128; ++e)
            s += rowS[e] * Wo[e * 64 + lane];
        partS[w][lane] = s;
        __syncthreads();
        if (t < 64) {
            float tot = partS[0][t] + partS[1][t] + partS[2][t] + partS[3][t];
            Wl2[(t >> 3) * (N_DIM * D_DIM) + n * D_DIM + (t & 7)] = tot;
        }
    }
}

// ---------------------------------------------------------------------------
// K2: MFMA Hopfield + FUSED classifier epilogue. o never hits HBM: each block
// dots its local o[128][8] with Wl2[h, n-range, :] and atomicAdds y[b].
// Block 0 also adds c0acc (zeroed in prep, accumulated in K1's wl2 part).
// Pb stride 44 halves: all P-scratch LDS collisions <=2-way (free).
// ---------------------------------------------------------------------------
__global__ __launch_bounds__(256) void hopfield(const half_t* __restrict__ q16,
                                                const half_t* __restrict__ k16,
                                                const half_t* __restrict__ v16,
                                                const float* __restrict__ Wl2,
                                                const float* __restrict__ c0acc,
                                                float* __restrict__ y) {
    __shared__ half_t Kb[N_DIM * 8];
    __shared__ half_t Xi[128 * 8];
    __shared__ half_t KTb[16 * 536];
    __shared__ half_t Pb[4 * 32 * PB_STRIDE];
    const int t = threadIdx.x;
    const int lane = t & 63;
    const int w = t >> 6;
    const int g2 = lane >> 4;
    const int c16 = lane & 15;
    const int bh = blockIdx.x >> 2, seg = blockIdx.x & 3;
    const float C = 0.25f * 1.44269504088896f;
    const half_t* kg = k16 + (size_t)bh * (N_DIM * D_DIM);
    const half_t* vg = v16 + (size_t)bh * (N_DIM * D_DIM);
    const half_t* qg = q16 + (size_t)bh * (N_DIM * D_DIM) + seg * 128 * 8;
    const float* wl2p = Wl2 + (bh & 7) * (N_DIM * D_DIM) + seg * 128 * 8;

    for (int i = t; i < 16 * 536; i += 256) KTb[i] = (half_t)0.f;
    __syncthreads();
    {   // stage K rows + K^T + ones row
        int j0 = 2 * t;
        half8v r0 = *(const half8v*)(kg + j0 * 8);
        half8v r1 = *(const half8v*)(kg + j0 * 8 + 8);
        *(half8v*)&Kb[j0 * 8] = r0;
        *(half8v*)&Kb[j0 * 8 + 8] = r1;
        #pragma unroll
        for (int d = 0; d < 8; ++d) {
            KTb[d * 536 + j0] = r0[d];
            KTb[d * 536 + j0 + 1] = r1[d];
        }
        KTb[8 * 536 + j0] = (half_t)1.f;
        KTb[8 * 536 + j0 + 1] = (half_t)1.f;
    }
    if (t < 128) {   // stage Xi = C * q
        half8v hq = *(const half8v*)(qg + t * 8);
        half8v h;
        #pragma unroll
        for (int d = 0; d < 8; ++d) h[d] = (half_t)(C * (float)hq[d]);
        *(half8v*)&Xi[t * 8] = h;
    }
    __syncthreads();

    const half_t* zsrc = &KTb[9 * 536];   // 16B-aligned zeros
    half_t* myP = &Pb[w * 32 * PB_STRIDE];
    float fsum = 0.f;

    for (int it = 0; it < 4; ++it) {
        if (it == 3) {   // swap KTb rows 0-7 to V^T
            __syncthreads();
            int j0 = 2 * t;
            half8v r0 = *(const half8v*)(vg + j0 * 8);
            half8v r1 = *(const half8v*)(vg + j0 * 8 + 8);
            #pragma unroll
            for (int d = 0; d < 8; ++d) {
                KTb[d * 536 + j0] = r0[d];
                KTb[d * 536 + j0 + 1] = r1[d];
            }
            __syncthreads();
        }
        const half_t* x0p = (g2 == 0) ? &Xi[(w * 32 + c16) * 8] : zsrc;
        const half_t* x1p = (g2 == 0) ? &Xi[(w * 32 + 16 + c16) * 8] : zsrc;
        half8v bxi0 = *(const half8v*)x0p;
        half8v bxi1 = *(const half8v*)x1p;
        f32x4 U0 = {0.f, 0.f, 0.f, 0.f}, U1 = {0.f, 0.f, 0.f, 0.f};
        for (int j32 = 0; j32 < 16; ++j32) {
            #pragma unroll
            for (int hh = 0; hh < 2; ++hh) {
                int jt16 = j32 * 2 + hh;
                const half_t* akp = (g2 == 0) ? &Kb[(jt16 * 16 + c16) * 8] : zsrc;
                half8v ak = *(const half8v*)akp;
                f32x4 S0 = {0.f, 0.f, 0.f, 0.f}, S1 = {0.f, 0.f, 0.f, 0.f};
                S0 = __builtin_amdgcn_mfma_f32_16x16x32_f16(ak, bxi0, S0, 0, 0, 0);
                S1 = __builtin_amdgcn_mfma_f32_16x16x32_f16(ak, bxi1, S1, 0, 0, 0);
                half4v p0, p1;
                #pragma unroll
                for (int r = 0; r < 4; ++r) {
                    p0[r] = (half_t)__builtin_amdgcn_exp2f(S0[r]);
                    p1[r] = (half_t)__builtin_amdgcn_exp2f(S1[r]);
                }
                int joff = hh * 16 + g2 * 4;
                *(half4v*)&myP[c16 * PB_STRIDE + joff] = p0;
                *(half4v*)&myP[(16 + c16) * PB_STRIDE + joff] = p1;
            }
            half4v alo0 = *(const half4v*)&myP[c16 * PB_STRIDE + g2 * 8];
            half4v ahi0 = *(const half4v*)&myP[c16 * PB_STRIDE + g2 * 8 + 4];
            half4v alo1 = *(const half4v*)&myP[(16 + c16) * PB_STRIDE + g2 * 8];
            half4v ahi1 = *(const half4v*)&myP[(16 + c16) * PB_STRIDE + g2 * 8 + 4];
            half8v ap0 = __builtin_shufflevector(alo0, ahi0, 0, 1, 2, 3, 4, 5, 6, 7);
            half8v ap1 = __builtin_shufflevector(alo1, ahi1, 0, 1, 2, 3, 4, 5, 6, 7);
            half8v b2f = *(const half8v*)&KTb[c16 * 536 + j32 * 32 + g2 * 8];
            U0 = __builtin_amdgcn_mfma_f32_16x16x32_f16(ap0, b2f, U0, 0, 0, 0);
            U1 = __builtin_amdgcn_mfma_f32_16x16x32_f16(ap1, b2f, U1, 0, 0, 0);
        }
        int srcl = (lane & 48) | 8;
        #pragma unroll
        for (int r = 0; r < 4; ++r) {
            float l0 = __shfl(U0[r], srcl, 64);
            float l1 = __shfl(U1[r], srcl, 64);
            if (c16 < 8) {
                int i0 = w * 32 + g2 * 4 + r;
                int i1 = i0 + 16;
                if (it < 3) {
                    Xi[i0 * 8 + c16] = (half_t)(U0[r] * (C / l0));
                    Xi[i1 * 8 + c16] = (half_t)(U1[r] * (C / l1));
                } else {
                    // fused classifier: o[i][d] * Wl2[h][n][d]
                    fsum += (U0[r] / l0) * wl2p[i0 * 8 + c16]
                          + (U1[r] / l1) * wl2p[i1 * 8 + c16];
                }
            }
        }
    }
    float tot = block_reduce_256(fsum);
    if (t == 0) atomicAdd(&y[bh >> 3], tot);
    if (blockIdx.x == 0 && t < 32) {
        float c0 = c0acc[0];
        atomicAdd(&y[t], c0);
    }
}

// ---------------------------------------------------------------------------
extern "C" void kernel_launch(void* const* d_in, const int* in_sizes, int n_in,
                              void* d_out, int out_size, void* d_ws, size_t ws_size,
                              hipStream_t stream) {
    const float* x   = (const float*)d_in[0];
    const float* g_q = (const float*)d_in[1];
    const float* b_q = (const float*)d_in[2];
    const float* g_k = (const float*)d_in[3];
    const float* b_k = (const float*)d_in[4];
    const float* g_v = (const float*)d_in[5];
    const float* b_v = (const float*)d_in[6];
    const float* Wq  = (const float*)d_in[7];
    const float* bq  = (const float*)d_in[8];
    const float* Wk  = (const float*)d_in[9];
    const float* bk  = (const float*)d_in[10];
    const float* Wv  = (const float*)d_in[11];
    const float* bv  = (const float*)d_in[12];
    const float* Wo  = (const float*)d_in[13];
    const float* bo  = (const float*)d_in[14];
    const float* Wl  = (const float*)d_in[15];
    const float* bl  = (const float*)d_in[16];
    float* out = (float*)d_out;

    float* ws = (float*)d_ws;
    float*  colsum = ws;                      // 192
    float*  b2     = ws + 192;                // 192
    float*  c0acc  = ws + 384;                // 1 (+pad to 64)
    float*  Wl2    = ws + 448;                // 32768
    half_t* Wth    = (half_t*)(ws + 33216);   // 98304 halves = 49152 floats
    half_t* qkv16  = (half_t*)(ws + 82368);   // 3*1048576 halves = 786432 floats

    half_t* q16 = qkv16;
    half_t* k16 = qkv16 + 1048576;
    half_t* v16 = qkv16 + 2097152;

    prep_w    <<<192, 256, 0, stream>>>(Wq, Wk, Wv, g_q, g_k, g_v,
                                        b_q, b_k, b_v, bq, bk, bv, bl,
                                        Wth, colsum, b2, out, c0acc);
    ln_qkv_wl2<<<1536, 256, 0, stream>>>(x, Wth, b2, colsum, qkv16,
                                         Wl, Wo, bo, Wl2, c0acc);
    hopfield  <<<1024, 256, 0, stream>>>(q16, k16, v16, Wl2, c0acc, out);
}